// Round 13
// baseline (911.013 us; speedup 1.0000x reference)
//
#include <hip/hip_runtime.h>
#include <hip/hip_bf16.h>

#define DIM   1024
#define NTOK  8192

using bf16 = __hip_bfloat16;
typedef __attribute__((ext_vector_type(8))) short bf16x8;
typedef __attribute__((ext_vector_type(4))) float f32x4;

__device__ __forceinline__ unsigned short f2b(float x) {
  union { __hip_bfloat16 h; unsigned short u; } cv;
  cv.h = __float2bfloat16(x);
  return cv.u;
}

// ---------------- cast f32 -> bf16 ----------------
__global__ __launch_bounds__(256) void cast_f32_bf16(const float* __restrict__ in,
                                                     bf16* __restrict__ out, int n4) {
  int i = blockIdx.x * 256 + threadIdx.x;
  if (i < n4) {
    const float4 v = ((const float4*)in)[i];
    ushort4 p;
    p.x = f2b(v.x); p.y = f2b(v.y); p.z = f2b(v.z); p.w = f2b(v.w);
    ((ushort4*)out)[i] = p;
  }
}

// ------------- tiled transpose + cast: in[R][C] f32 -> out[C][R] bf16 -------------
__global__ __launch_bounds__(256) void transpose_cast32(const float* __restrict__ in,
                                                        bf16* __restrict__ out, int R, int C) {
  __shared__ float t[32][33];
  const int tilesC = C / 32;
  const int c0 = (blockIdx.x % tilesC) * 32;
  const int r0 = (blockIdx.x / tilesC) * 32;
  const int tx = threadIdx.x & 31, ty = threadIdx.x >> 5;
  #pragma unroll
  for (int i = 0; i < 4; ++i) {
    int r = ty + i * 8;
    t[r][tx] = in[(size_t)(r0 + r) * C + c0 + tx];
  }
  __syncthreads();
  #pragma unroll
  for (int i = 0; i < 4; ++i) {
    int cr = ty + i * 8;
    out[(size_t)(c0 + cr) * R + r0 + tx] = __float2bfloat16(t[tx][cr]);
  }
}

// ------------- bf16 transpose, 64x64 tiles, vectorized both sides, dual-input -------------
__global__ __launch_bounds__(256) void transpose_bf16(const short* __restrict__ in,
                                                      short* __restrict__ out,
                                                      const short* __restrict__ in2,
                                                      short* __restrict__ out2,
                                                      int R, int C) {
  __shared__ short t[64][72];
  const int tilesC = C >> 6;
  const int tilesPer = (R >> 6) * tilesC;
  int bid = blockIdx.x;
  const short* src = in; short* dst = out;
  if (bid >= tilesPer) { bid -= tilesPer; src = in2; dst = out2; }
  const int r0 = (bid / tilesC) << 6, c0 = (bid % tilesC) << 6;
  const int tr = threadIdx.x >> 3, tc8 = (threadIdx.x & 7) << 3;
  #pragma unroll
  for (int p = 0; p < 2; ++p) {
    int r = tr + p * 32;
    int sc = tc8 ^ (((r >> 3) & 7) << 3);
    *(bf16x8*)&t[r][sc] = *(const bf16x8*)&src[(size_t)(r0 + r) * C + c0 + tc8];
  }
  __syncthreads();
  #pragma unroll
  for (int p = 0; p < 2; ++p) {
    int oc = tr + p * 32;
    bf16x8 v;
    #pragma unroll
    for (int e = 0; e < 8; ++e) {
      int a = tc8 + e;
      v[e] = t[a][oc ^ (((a >> 3) & 7) << 3)];
    }
    *(bf16x8*)&dst[(size_t)(c0 + oc) * R + r0 + tc8] = v;
  }
}

// ---------------- pack 6 bias vectors ----------------
__global__ __launch_bounds__(256) void pack_bias(const float* b0, const float* b1,
                                                 const float* b2, const float* b3,
                                                 const float* b4, const float* b5,
                                                 float* __restrict__ out) {
  int i = blockIdx.x * 256 + threadIdx.x;
  if (i < 6 * DIM) {
    int s = i >> 10, o = i & 1023;
    const float* p = (s == 0) ? b0 : (s == 1) ? b1 : (s == 2) ? b2 : (s == 3) ? b3 : (s == 4) ? b4 : b5;
    out[i] = p[o];
  }
}

// ========== 256x256 NT GEMM, merged 2-phase, PERSISTENT tiles (TPB>1) ==========
// C[M,N] = A[M,K] @ Bt[N,K]^T. BK=64, 512 thr = 8 waves (2M x 4N), wave tile 128x64.
// TPB tiles per block (same bm A-panel, consecutive bn). Single continuous staging
// stream over GT = TPB*NT k-tiles; per-tile epilogue uses a separate 32KB scratch
// with RAW s_barrier + lgkmcnt(0) (NOT __syncthreads, which drains vmcnt and would
// kill the staging overlap). LDS = 128KB dbuf + 32KB scratch = 160 KiB (HW max).
// acc[m] (m=0..7) maps to the wave's 128-row half: row = bm + wr*128 + m*16 + kg*4 + e
// (r12 BUG: epilogue indexed acc[(h?4:0)+...] -> OOB acc[11] for h=1; fixed to
//  acc[(p&3)*2+mm] which is h-independent).
// EPI: 2 = sigmoid->f32 | 3 = f32 | 4 = sigmoid->f32+bf16 | 5 = fused QKV proj
template<int EPI, bool DUAL, int TPB, int NTLOG>
__global__ __launch_bounds__(512, 1) void gemm256(
    const bf16* __restrict__ A,  const bf16* __restrict__ Bt,
    const bf16* __restrict__ A2, const bf16* __restrict__ Bt2,
    int M, int N, int K, int tilesN, int perDir,
    const float* __restrict__ bias, const float* __restrict__ bias2, float scale,
    float* __restrict__ Cf, float* __restrict__ Cf2,
    bf16* __restrict__ Cb, bf16* __restrict__ Cb2,
    bf16* __restrict__ Cq, bf16* __restrict__ Ck, bf16* __restrict__ Cv,
    bf16* __restrict__ Cq2, bf16* __restrict__ Ck2, bf16* __restrict__ Cv2)
{
  const int NT = 1 << NTLOG;
  const int GT = TPB << NTLOG;
  __shared__ bf16 lds[2][2 * 16384];   // 128 KiB loop double-buffer
  __shared__ float esc[8192];          // 32 KiB epilogue scratch (32 rows x 256)

  const int t    = threadIdx.x;
  const int lane = t & 63, wid = t >> 6;
  const int wr = wid >> 2, wc = wid & 3;
  const int lr = lane & 15, kg = lane >> 4;

  int bid = blockIdx.x;
  if (TPB == 1) {  // XCD swizzle only for non-persistent (persistent: natural map is L2-optimal)
    const int nwg = gridDim.x;
    const int q = nwg >> 3;
    bid = (bid & 7) * q + (bid >> 3);
  }
  int g0 = bid * TPB;

  const bf16* Au = A; const bf16* BtU = Bt;
  float* CfU = Cf; bf16* CbU = Cb;
  if (DUAL && g0 >= perDir) { g0 -= perDir; Au = A2; BtU = Bt2; CfU = Cf2; CbU = Cb2; }

  const int bm  = (g0 / tilesN) << 8;   // fixed per block (TPB | tilesN alignment)
  const int bn0 = (g0 % tilesN) << 8;

  // proj: dual-by-row select
  const float* biasU = bias;
  bf16 *CqU = Cq, *CkU = Ck, *CvU = Cv;
  int bmL = bm;
  if (EPI == 5 && bm >= (M >> 1)) {
    BtU = Bt2; biasU = bias2; CqU = Cq2; CkU = Ck2; CvU = Cv2; bmL = bm - (M >> 1);
  }

  // staging: thread t covers one 16B chunk of each 64-row region; source col pre-swizzled
  const int srow = t >> 3;
  const int scol = ((t & 7) ^ (srow & 7)) * 8;
  const size_t rA = (size_t)(bm + srow) * K + scol;
  const size_t rB = (size_t)(bn0 + srow) * K + scol;

  // STAGE for global k-tile index Gi: tile j = Gi>>NTLOG (B shifts by 256 rows/tile; A fixed)
#define STAGE(Gi, isB, R0) do {                                                          \
    const int jj_ = (Gi) >> NTLOG;                                                       \
    const int tk_ = (Gi) & (NT - 1);                                                     \
    const bf16* g_ = ((isB) ? BtU + rB + (size_t)jj_ * ((size_t)K << 8) : Au + rA)       \
                     + (size_t)(R0) * K + (size_t)tk_ * 64;                              \
    __builtin_amdgcn_global_load_lds(                                                    \
        (const __attribute__((address_space(1))) unsigned int*)g_,                       \
        (__attribute__((address_space(3))) unsigned int*)(&lds[(Gi) & 1][((isB) ? 16384 : 0) + (R0) * 64 + t * 8]), \
        16, 0, 0);                                                                       \
  } while (0)

  // fragment read offsets (swizzled): col16 = (kk*4+kg) ^ (lr&7)
  const int fcol0 = ((kg)     ^ (lr & 7)) * 8;
  const int fcol1 = ((4 + kg) ^ (lr & 7)) * 8;
  const int arow = (wr * 128 + lr) * 64;
  const int brow = (wc * 64 + lr) * 64;

  f32x4 acc[8][4] = {};

  // ---- prologue: k-tile0 full -> buf0; k-tile1 first halves -> buf1 ----
  STAGE(0, false, 0);   STAGE(0, false, 128);
  STAGE(0, false, 64);  STAGE(0, false, 192);
  STAGE(0, true, 0);    STAGE(0, true, 64);
  STAGE(0, true, 128);  STAGE(0, true, 192);
  if (GT > 1) {
    STAGE(1, false, 0); STAGE(1, false, 128);
    STAGE(1, true, 0);  STAGE(1, true, 64);
    asm volatile("s_waitcnt vmcnt(4)" ::: "memory");
  } else {
    asm volatile("s_waitcnt vmcnt(0)" ::: "memory");
  }
  __builtin_amdgcn_sched_barrier(0);
  __builtin_amdgcn_s_barrier();

  for (int G = 0; G < GT; ++G) {
    const int cur = G & 1;
    const bf16* bufA = &lds[cur][0];
    const bf16* bufB = &lds[cur][16384];
    bf16x8 b0[4], b1[4];

    { // Phase A: mh=0, both k-halves (32 MFMA) | stage Gi=G+1 second halves -> buf cur^1
      bf16x8 a0[4], a1[4];
      #pragma unroll
      for (int n = 0; n < 4; ++n) b0[n] = *(const bf16x8*)(bufB + brow + n * 1024 + fcol0);
      #pragma unroll
      for (int n = 0; n < 4; ++n) b1[n] = *(const bf16x8*)(bufB + brow + n * 1024 + fcol1);
      #pragma unroll
      for (int mi = 0; mi < 4; ++mi) a0[mi] = *(const bf16x8*)(bufA + arow + mi * 1024 + fcol0);
      #pragma unroll
      for (int mi = 0; mi < 4; ++mi) a1[mi] = *(const bf16x8*)(bufA + arow + mi * 1024 + fcol1);
      if (G + 1 < GT) {
        STAGE(G + 1, true, 128); STAGE(G + 1, true, 192);
        STAGE(G + 1, false, 64); STAGE(G + 1, false, 192);
      }
      __builtin_amdgcn_s_barrier();
      asm volatile("s_waitcnt lgkmcnt(0)" ::: "memory");
      __builtin_amdgcn_sched_barrier(0);
      __builtin_amdgcn_s_setprio(1);
      #pragma unroll
      for (int mi = 0; mi < 4; ++mi)
        #pragma unroll
        for (int n = 0; n < 4; ++n)
          acc[mi][n] = __builtin_amdgcn_mfma_f32_16x16x32_bf16(a0[mi], b0[n], acc[mi][n], 0, 0, 0);
      #pragma unroll
      for (int mi = 0; mi < 4; ++mi)
        #pragma unroll
        for (int n = 0; n < 4; ++n)
          acc[mi][n] = __builtin_amdgcn_mfma_f32_16x16x32_bf16(a1[mi], b1[n], acc[mi][n], 0, 0, 0);
      __builtin_amdgcn_s_setprio(0);
      __builtin_amdgcn_s_barrier();
    }
    { // Phase B: mh=1, b0/b1 from regs (32 MFMA) | stage Gi=G+2 first halves -> buf cur
      bf16x8 a0[4], a1[4];
      #pragma unroll
      for (int mi = 0; mi < 4; ++mi) a0[mi] = *(const bf16x8*)(bufA + arow + 4096 + mi * 1024 + fcol0);
      #pragma unroll
      for (int mi = 0; mi < 4; ++mi) a1[mi] = *(const bf16x8*)(bufA + arow + 4096 + mi * 1024 + fcol1);
      if (G + 2 < GT) {
        STAGE(G + 2, false, 0); STAGE(G + 2, false, 128);
        STAGE(G + 2, true, 0);  STAGE(G + 2, true, 64);
      }
      __builtin_amdgcn_s_barrier();
      asm volatile("s_waitcnt lgkmcnt(0)" ::: "memory");
      __builtin_amdgcn_sched_barrier(0);
      __builtin_amdgcn_s_setprio(1);
      #pragma unroll
      for (int mi = 0; mi < 4; ++mi)
        #pragma unroll
        for (int n = 0; n < 4; ++n)
          acc[4 + mi][n] = __builtin_amdgcn_mfma_f32_16x16x32_bf16(a0[mi], b0[n], acc[4 + mi][n], 0, 0, 0);
      #pragma unroll
      for (int mi = 0; mi < 4; ++mi)
        #pragma unroll
        for (int n = 0; n < 4; ++n)
          acc[4 + mi][n] = __builtin_amdgcn_mfma_f32_16x16x32_bf16(a1[mi], b1[n], acc[4 + mi][n], 0, 0, 0);
      __builtin_amdgcn_s_setprio(0);
      if (G + 2 < GT) { asm volatile("s_waitcnt vmcnt(4)" ::: "memory"); }
      else            { asm volatile("s_waitcnt vmcnt(0)" ::: "memory"); }
      __builtin_amdgcn_sched_barrier(0);
      __builtin_amdgcn_s_barrier();
    }

    // ======== per-tile epilogue (32-row passes; raw barriers keep staging in flight) ========
    if ((G & (NT - 1)) == NT - 1) {
      const int j   = G >> NTLOG;
      const int bnj = bn0 + (j << 8);

      float bN[4];
      if (EPI == 5) {
        #pragma unroll
        for (int n = 0; n < 4; ++n) bN[n] = biasU[bnj + wc * 64 + n * 16 + lr];
      }

      #pragma unroll
      for (int p = 0; p < 8; ++p) {
        const int h = p >> 2;
        if (wr == h) {
          #pragma unroll
          for (int mm = 0; mm < 2; ++mm)
            #pragma unroll
            for (int n = 0; n < 4; ++n)
              #pragma unroll
              for (int e = 0; e < 4; ++e) {
                const int rl  = mm * 16 + kg * 4 + e;        // 0..31
                const int col = wc * 64 + n * 16 + lr;       // 0..255
                float v = acc[(p & 3) * 2 + mm][n][e];       // m = row_within_half/16 (h-independent)
                if (EPI == 2 || EPI == 4) v = 1.0f / (1.0f + __expf(-v * scale));
                if (EPI == 5) v += bN[n];
                esc[rl * 256 + (col ^ (((rl >> 2) & 3) << 4))] = v;
              }
        }
        asm volatile("s_waitcnt lgkmcnt(0)" ::: "memory");
        __builtin_amdgcn_sched_barrier(0);
        __builtin_amdgcn_s_barrier();
        #pragma unroll
        for (int rr = 0; rr < 4; ++rr) {
          const int rl  = wid * 4 + rr;                      // 0..31
          const int cb  = lane * 4;
          const int cbs = cb ^ (((rl >> 2) & 3) << 4);
          const f32x4 v = *(const f32x4*)&esc[rl * 256 + cbs];
          const int gr  = bm + h * 128 + (p & 3) * 32 + rl;
          const int gc  = bnj + cb;
          if (EPI == 2 || EPI == 4) {
            __builtin_nontemporal_store(v, (f32x4*)&CfU[(size_t)gr * N + gc]);
            if (EPI == 4) {
              ushort4 pk; pk.x = f2b(v[0]); pk.y = f2b(v[1]); pk.z = f2b(v[2]); pk.w = f2b(v[3]);
              *(ushort4*)&CbU[(size_t)gr * N + gc] = pk;
            }
          } else if (EPI == 3) {
            __builtin_nontemporal_store(v, (f32x4*)&CfU[(size_t)gr * N + gc]);
          } else if (EPI == 5) {
            const int seg = bnj >> 10;
            const int cl  = (bnj & 1023) + cb;
            const int r   = bmL + h * 128 + (p & 3) * 32 + rl;
            bf16* sel = (seg == 0) ? CqU : (seg == 1) ? CkU : CvU;
            ushort4 pk; pk.x = f2b(v[0]); pk.y = f2b(v[1]); pk.z = f2b(v[2]); pk.w = f2b(v[3]);
            *(ushort4*)&sel[(size_t)r * DIM + cl] = pk;
          }
        }
        asm volatile("s_waitcnt lgkmcnt(0)" ::: "memory");
        __builtin_amdgcn_sched_barrier(0);
        __builtin_amdgcn_s_barrier();
      }

      // reset accumulator for next tile
      #pragma unroll
      for (int m = 0; m < 8; ++m)
        #pragma unroll
        for (int n = 0; n < 4; ++n)
          #pragma unroll
          for (int e = 0; e < 4; ++e) acc[m][n][e] = 0.0f;
    }
  }
#undef STAGE
}

// ================= legacy 128x128 GEMM (low-ws fallback only) =================
template<int EPI, bool A_F32>
__global__ __launch_bounds__(256) void gemm_nt(
    const void* __restrict__ Ap, const bf16* __restrict__ Bt,
    int M, int N, int K,
    float scale, float* __restrict__ Cf)
{
  __shared__ bf16 As[128 * 32];
  __shared__ bf16 Bs[128 * 32];
  const int tid  = threadIdx.x;
  const int lane = tid & 63, wid = tid >> 6;
  const int wrr = wid >> 1, wcc = wid & 1;
  const int tilesN = N >> 7;
  const int nwg = gridDim.x;
  int bid = blockIdx.x;
  if ((nwg & 7) == 0) { const int q = nwg >> 3; bid = (bid & 7) * q + (bid >> 3); }
  const int bm = (bid / tilesN) * 128, bn = (bid % tilesN) * 128;
  f32x4 acc[4][4] = {};
  const bf16*  Ab16 = (const bf16*)Ap;
  const float* Af32 = (const float*)Ap;
  const int srow = tid >> 2, sc8 = (tid & 3) * 8;
  const int frow = tid >> 3, fc4 = (tid & 7) * 4;

  for (int k0 = 0; k0 < K; k0 += 32) {
    if (A_F32) {
      #pragma unroll
      for (int is = 0; is < 4; ++is) {
        int row = is * 32 + frow;
        const float4 v = *(const float4*)(Af32 + (size_t)(bm + row) * K + k0 + fc4);
        ushort4 p; p.x = f2b(v.x); p.y = f2b(v.y); p.z = f2b(v.z); p.w = f2b(v.w);
        *(ushort4*)(&As[row * 32 + fc4]) = p;
      }
    } else {
      #pragma unroll
      for (int is = 0; is < 2; ++is) {
        int row = is * 64 + srow;
        const bf16* g = Ab16 + (size_t)(bm + row) * K + k0 + sc8;
        __builtin_amdgcn_global_load_lds(
            (const __attribute__((address_space(1))) unsigned int*)g,
            (__attribute__((address_space(3))) unsigned int*)(&As[row * 32 + sc8]), 16, 0, 0);
      }
    }
    #pragma unroll
    for (int is = 0; is < 2; ++is) {
      int row = is * 64 + srow;
      const bf16* g = Bt + (size_t)(bn + row) * K + k0 + sc8;
      __builtin_amdgcn_global_load_lds(
          (const __attribute__((address_space(1))) unsigned int*)g,
          (__attribute__((address_space(3))) unsigned int*)(&Bs[row * 32 + sc8]), 16, 0, 0);
    }
    __syncthreads();
    const int lrr = lane & 15, kgg = lane >> 4;
    bf16x8 af[4], bfv[4];
    #pragma unroll
    for (int i = 0; i < 4; ++i)
      af[i] = *(const bf16x8*)(&As[(wrr * 64 + i * 16 + lrr) * 32 + kgg * 8]);
    #pragma unroll
    for (int j = 0; j < 4; ++j)
      bfv[j] = *(const bf16x8*)(&Bs[(wcc * 64 + j * 16 + lrr) * 32 + kgg * 8]);
    #pragma unroll
    for (int i = 0; i < 4; ++i)
      #pragma unroll
      for (int j = 0; j < 4; ++j)
        acc[i][j] = __builtin_amdgcn_mfma_f32_16x16x32_bf16(af[i], bfv[j], acc[i][j], 0, 0, 0);
    __syncthreads();
  }
  const int r0 = bm + wrr * 64 + (lane >> 4) * 4;
  const int c0 = bn + wcc * 64 + (lane & 15);
  if (EPI == 2) {
    #pragma unroll
    for (int i = 0; i < 4; ++i)
      #pragma unroll
      for (int j = 0; j < 4; ++j)
        #pragma unroll
        for (int e = 0; e < 4; ++e) {
          float pr = 1.0f / (1.0f + __expf(-acc[i][j][e] * scale));
          Cf[(size_t)(r0 + i * 16 + e) * N + c0 + j * 16] = pr;
        }
  } else {
    #pragma unroll
    for (int i = 0; i < 4; ++i)
      #pragma unroll
      for (int j = 0; j < 4; ++j)
        #pragma unroll
        for (int e = 0; e < 4; ++e)
          Cf[(size_t)(r0 + i * 16 + e) * N + c0 + j * 16] = acc[i][j][e];
  }
}

extern "C" void kernel_launch(void* const* d_in, const int* in_sizes, int n_in,
                              void* d_out, int out_size, void* d_ws, size_t ws_size,
                              hipStream_t stream) {
  const float* x1 = (const float*)d_in[0];
  const float* x2 = (const float*)d_in[1];
  const float* W[6] = { (const float*)d_in[2],  (const float*)d_in[4],  (const float*)d_in[6],
                        (const float*)d_in[8],  (const float*)d_in[10], (const float*)d_in[12] };
  const float* B[6] = { (const float*)d_in[3],  (const float*)d_in[5],  (const float*)d_in[7],
                        (const float*)d_in[9],  (const float*)d_in[11], (const float*)d_in[13] };

  const size_t MD = (size_t)NTOK * DIM;
  const size_t DD = (size_t)DIM * DIM;
  const size_t NN = (size_t)NTOK * NTOK;

  bf16* ws   = (bf16*)d_ws;
  bf16* x1b  = ws;                         // contiguous with x2b -> proj A (16384 rows)
  bf16* x2b  = x1b + MD;
  bf16* wt1  = x2b + MD;
  bf16* wt2  = wt1 + 3 * DD;
  float* bstack = (float*)(wt2 + 3 * DD);  // 6144 f32 in 16384-bf16 slot
  bf16* q1   = wt2 + 3 * DD + 16384;
  bf16* k1   = q1 + MD;
  bf16* q2   = k1 + MD;
  bf16* k2   = q2 + MD;
  bf16* v1r  = k2 + MD;
  bf16* v2r  = v1r + MD;
  bf16* v1T  = v2r + MD;
  bf16* v2T  = v1T + MD;
  bf16* probsb = v2T + MD;                 // 2 x 64M bf16

  const size_t topBytes = ((size_t)(10 * MD + 6 * DD + 16384) + 2 * NN) * 2;
  const bool top = (ws_size >= topBytes);  // ~440 MB; measured ws ≈ 2.4 GB

  float* out    = (float*)d_out;
  float* ctx2   = out;
  float* probs2 = ctx2 + MD;
  float* ctx1   = probs2 + NN;
  float* probs1 = ctx1 + MD;

  const float scale = 1.0f / 32.0f;

  {
    int n4 = (int)(MD / 4);
    int blks = (n4 + 255) / 256;
    cast_f32_bf16<<<blks, 256, 0, stream>>>(x1, x1b, n4);
    cast_f32_bf16<<<blks, 256, 0, stream>>>(x2, x2b, n4);
  }
  {
    int blks = (DIM / 32) * (DIM / 32);
    transpose_cast32<<<blks, 256, 0, stream>>>(W[0], wt1 + 0 * DD, DIM, DIM);
    transpose_cast32<<<blks, 256, 0, stream>>>(W[1], wt1 + 1 * DD, DIM, DIM);
    transpose_cast32<<<blks, 256, 0, stream>>>(W[2], wt1 + 2 * DD, DIM, DIM);
    transpose_cast32<<<blks, 256, 0, stream>>>(W[3], wt2 + 0 * DD, DIM, DIM);
    transpose_cast32<<<blks, 256, 0, stream>>>(W[4], wt2 + 1 * DD, DIM, DIM);
    transpose_cast32<<<blks, 256, 0, stream>>>(W[5], wt2 + 2 * DD, DIM, DIM);
  }
  pack_bias<<<24, 256, 0, stream>>>(B[0], B[1], B[2], B[3], B[4], B[5], bstack);

  // fused QKV projection: A = [x1b;x2b] (16384 x 1024), N = 3072. grid 768, TPB=1.
  gemm256<5, false, 1, 4><<<64 * 12, 512, 0, stream>>>(
      x1b, wt1, nullptr, wt2, 2 * NTOK, 3 * DIM, DIM, 12, 768,
      bstack, bstack + 3 * DIM, 0.f,
      nullptr, nullptr, nullptr, nullptr,
      q1, k1, v1r, q2, k2, v2r);

  // v transpose: [8192,1024] -> [1024,8192], both inputs
  transpose_bf16<<<2 * (NTOK / 64) * (DIM / 64), 256, 0, stream>>>(
      (const short*)v1r, (short*)v1T, (const short*)v2r, (short*)v2T, NTOK, DIM);

  const int perQK = (NTOK / 256) * (NTOK / 256);  // 1024 tiles per dir
  const int perPV = (NTOK / 256) * (DIM / 256);   // 128 tiles per dir

  if (top) {
    // PERSISTENT fused dual QK: 2048 tiles / TPB=8 -> grid 256 (1 block/CU).
    gemm256<4, true, 8, 4><<<256, 512, 0, stream>>>(
        q1, k2, q2, k1, NTOK, NTOK, DIM, 32, perQK,
        nullptr, nullptr, scale,
        probs2, probs1, probsb, probsb + NN,
        nullptr, nullptr, nullptr, nullptr, nullptr, nullptr);
    // fused dual PV: K=8192, NT=128, grid 256 (1 block/CU), TPB=1.
    gemm256<3, true, 1, 7><<<2 * perPV, 512, 0, stream>>>(
        probsb, v2T, probsb + NN, v1T, NTOK, DIM, NTOK, 4, perPV,
        nullptr, nullptr, 0.f,
        ctx2, ctx1, nullptr, nullptr,
        nullptr, nullptr, nullptr, nullptr, nullptr, nullptr);
  } else {
    // fallback: f32 probs only; PV re-reads f32 probs from d_out with convert-on-stage
    gemm256<2, false, 1, 4><<<perQK, 512, 0, stream>>>(
        q1, k2, nullptr, nullptr, NTOK, NTOK, DIM, 32, perQK,
        nullptr, nullptr, scale,
        probs2, nullptr, nullptr, nullptr,
        nullptr, nullptr, nullptr, nullptr, nullptr, nullptr);
    gemm_nt<3, true><<<(NTOK / 128) * (DIM / 128), 256, 0, stream>>>(
        probs2, v2T, NTOK, DIM, NTOK, 0.f, ctx2);
    gemm256<2, false, 1, 4><<<perQK, 512, 0, stream>>>(
        q2, k1, nullptr, nullptr, NTOK, NTOK, DIM, 32, perQK,
        nullptr, nullptr, scale,
        probs1, nullptr, nullptr, nullptr,
        nullptr, nullptr, nullptr, nullptr, nullptr, nullptr);
    gemm_nt<3, true><<<(NTOK / 128) * (DIM / 128), 256, 0, stream>>>(
        probs1, v1T, NTOK, DIM, NTOK, 0.f, ctx1);
  }
}

// Round 14
// 775.213 us; speedup vs baseline: 1.1752x; 1.1752x over previous
//
#include <hip/hip_runtime.h>
#include <hip/hip_bf16.h>

#define DIM   1024
#define NTOK  8192

using bf16 = __hip_bfloat16;
typedef __attribute__((ext_vector_type(8))) short bf16x8;
typedef __attribute__((ext_vector_type(4))) float f32x4;

__device__ __forceinline__ unsigned short f2b(float x) {
  union { __hip_bfloat16 h; unsigned short u; } cv;
  cv.h = __float2bfloat16(x);
  return cv.u;
}

// ---------------- cast f32 -> bf16, dual-source single dispatch ----------------
__global__ __launch_bounds__(256) void cast2_f32_bf16(const float* __restrict__ in0,
                                                      const float* __restrict__ in1,
                                                      bf16* __restrict__ out, int n4) {
  int i = blockIdx.x * 256 + threadIdx.x;
  if (i < 2 * n4) {
    const float* src = (i < n4) ? in0 : in1;
    int j = (i < n4) ? i : i - n4;
    const float4 v = ((const float4*)src)[j];
    ushort4 p;
    p.x = f2b(v.x); p.y = f2b(v.y); p.z = f2b(v.z); p.w = f2b(v.w);
    ((ushort4*)out)[i] = p;   // out = x1b; x2b contiguous at out + n4*4 elems
  }
}

// ------ tiled transpose + cast for 6 DxD weights in one dispatch ------
// dest = base + widx*D*D, widx = blockIdx / blksPerW
__global__ __launch_bounds__(256) void transpose_cast6(
    const float* __restrict__ w0, const float* __restrict__ w1,
    const float* __restrict__ w2, const float* __restrict__ w3,
    const float* __restrict__ w4, const float* __restrict__ w5,
    bf16* __restrict__ base) {
  __shared__ float t[32][33];
  const int tilesC = DIM / 32;
  const int blksPerW = tilesC * (DIM / 32);
  const int widx = blockIdx.x / blksPerW;
  const int lb   = blockIdx.x % blksPerW;
  const float* in = (widx == 0) ? w0 : (widx == 1) ? w1 : (widx == 2) ? w2
                   : (widx == 3) ? w3 : (widx == 4) ? w4 : w5;
  bf16* out = base + (size_t)widx * DIM * DIM;
  const int c0 = (lb % tilesC) * 32;
  const int r0 = (lb / tilesC) * 32;
  const int tx = threadIdx.x & 31, ty = threadIdx.x >> 5;
  #pragma unroll
  for (int i = 0; i < 4; ++i) {
    int r = ty + i * 8;
    t[r][tx] = in[(size_t)(r0 + r) * DIM + c0 + tx];
  }
  __syncthreads();
  #pragma unroll
  for (int i = 0; i < 4; ++i) {
    int cr = ty + i * 8;
    out[(size_t)(c0 + cr) * DIM + r0 + tx] = __float2bfloat16(t[tx][cr]);
  }
}

// ------------- bf16 transpose, 64x64 tiles, vectorized both sides, dual-input -------------
__global__ __launch_bounds__(256) void transpose_bf16(const short* __restrict__ in,
                                                      short* __restrict__ out,
                                                      const short* __restrict__ in2,
                                                      short* __restrict__ out2,
                                                      int R, int C) {
  __shared__ short t[64][72];
  const int tilesC = C >> 6;
  const int tilesPer = (R >> 6) * tilesC;
  int bid = blockIdx.x;
  const short* src = in; short* dst = out;
  if (bid >= tilesPer) { bid -= tilesPer; src = in2; dst = out2; }
  const int r0 = (bid / tilesC) << 6, c0 = (bid % tilesC) << 6;
  const int tr = threadIdx.x >> 3, tc8 = (threadIdx.x & 7) << 3;
  #pragma unroll
  for (int p = 0; p < 2; ++p) {
    int r = tr + p * 32;
    int sc = tc8 ^ (((r >> 3) & 7) << 3);
    *(bf16x8*)&t[r][sc] = *(const bf16x8*)&src[(size_t)(r0 + r) * C + c0 + tc8];
  }
  __syncthreads();
  #pragma unroll
  for (int p = 0; p < 2; ++p) {
    int oc = tr + p * 32;
    bf16x8 v;
    #pragma unroll
    for (int e = 0; e < 8; ++e) {
      int a = tc8 + e;
      v[e] = t[a][oc ^ (((a >> 3) & 7) << 3)];
    }
    *(bf16x8*)&dst[(size_t)(c0 + oc) * R + r0 + tc8] = v;
  }
}

// ---------------- pack 6 bias vectors ----------------
__global__ __launch_bounds__(256) void pack_bias(const float* b0, const float* b1,
                                                 const float* b2, const float* b3,
                                                 const float* b4, const float* b5,
                                                 float* __restrict__ out) {
  int i = blockIdx.x * 256 + threadIdx.x;
  if (i < 6 * DIM) {
    int s = i >> 10, o = i & 1023;
    const float* p = (s == 0) ? b0 : (s == 1) ? b1 : (s == 2) ? b2 : (s == 3) ? b3 : (s == 4) ? b4 : b5;
    out[i] = p[o];
  }
}

// ================= 256x256 8-phase NT GEMM (r9 structure, best measured) =================
// C[M,N] = A[M,K] @ Bt[N,K]^T. BK=64, 512 thr = 8 waves (2M x 4N), wave tile 128x64.
// LDS 2 x 64KB double-buffer, XOR-swizzled (col16 ^= row&7) via pre-swizzled
// global source + swizzled ds_read (rule #21). Counted vmcnt(4), never 0 in loop.
// EPI: 2 = sigmoid->f32 | 3 = f32 | 4 = sigmoid->f32+bf16 | 5 = fused QKV proj
template<int EPI, bool DUAL>
__global__ __launch_bounds__(512, 1) void gemm256(
    const bf16* __restrict__ A,  const bf16* __restrict__ Bt,
    const bf16* __restrict__ A2, const bf16* __restrict__ Bt2,
    int M, int N, int K, int tilesN, int perDir,
    const float* __restrict__ bias, const float* __restrict__ bias2, float scale,
    float* __restrict__ Cf, float* __restrict__ Cf2,
    bf16* __restrict__ Cb, bf16* __restrict__ Cb2,
    bf16* __restrict__ Cq, bf16* __restrict__ Ck, bf16* __restrict__ Cv,
    bf16* __restrict__ Cq2, bf16* __restrict__ Ck2, bf16* __restrict__ Cv2)
{
  __shared__ bf16 lds[2][2 * 16384];
  const int t    = threadIdx.x;
  const int lane = t & 63, wid = t >> 6;
  const int wr = wid >> 2, wc = wid & 3;
  const int lr = lane & 15, kg = lane >> 4;

  // XCD-aware bijective swizzle (all grids are multiples of 8)
  const int nwg = gridDim.x;
  int bid = blockIdx.x;
  { const int q = nwg >> 3; bid = (bid & 7) * q + (bid >> 3); }

  const bf16* Au = A; const bf16* BtU = Bt;
  float* CfU = Cf; bf16* CbU = Cb;
  if (DUAL && bid >= perDir) { bid -= perDir; Au = A2; BtU = Bt2; CfU = Cf2; CbU = Cb2; }

  const int bm = (bid / tilesN) << 8;
  const int bn = (bid % tilesN) << 8;

  // proj: dual-by-row select
  const float* biasU = bias;
  bf16 *CqU = Cq, *CkU = Ck, *CvU = Cv;
  int bmL = bm;
  if (EPI == 5 && bm >= (M >> 1)) {
    BtU = Bt2; biasU = bias2; CqU = Cq2; CkU = Ck2; CvU = Cv2; bmL = bm - (M >> 1);
  }

  // staging: thread t covers one 16B chunk of each 64-row region; source col pre-swizzled
  const int srow = t >> 3;
  const int scol = ((t & 7) ^ (srow & 7)) * 8;
  const size_t bA = (size_t)(bm + srow) * K + scol;
  const size_t bB = (size_t)(bn + srow) * K + scol;

#define STAGE(buf, isB, R0, tt_) do {                                                   \
    const bf16* g_ = ((isB) ? BtU + bB : Au + bA) + (size_t)(R0) * K + (size_t)(tt_) * 64; \
    __builtin_amdgcn_global_load_lds(                                                   \
        (const __attribute__((address_space(1))) unsigned int*)g_,                      \
        (__attribute__((address_space(3))) unsigned int*)(&lds[buf][((isB) ? 16384 : 0) + (R0) * 64 + t * 8]), \
        16, 0, 0);                                                                      \
  } while (0)

  // fragment read offsets (swizzled): col16 = (kk*4+kg) ^ (lr&7)
  const int fcol0 = ((kg)     ^ (lr & 7)) * 8;
  const int fcol1 = ((4 + kg) ^ (lr & 7)) * 8;
  const int arow = (wr * 128 + lr) * 64;
  const int brow = (wc * 64 + lr) * 64;

  f32x4 acc[8][4] = {};
  const int NT = K >> 6;

  // ---- prologue: tile0 full -> buf0; tile1 half -> buf1 ----
  STAGE(0, false, 0, 0);   STAGE(0, false, 128, 0);
  STAGE(0, false, 64, 0);  STAGE(0, false, 192, 0);
  STAGE(0, true, 0, 0);    STAGE(0, true, 64, 0);
  STAGE(0, true, 128, 0);  STAGE(0, true, 192, 0);
  if (NT > 1) {
    STAGE(1, false, 0, 1); STAGE(1, false, 128, 1);
    STAGE(1, true, 0, 1);  STAGE(1, true, 64, 1);
    asm volatile("s_waitcnt vmcnt(4)" ::: "memory");
  } else {
    asm volatile("s_waitcnt vmcnt(0)" ::: "memory");
  }
  __builtin_amdgcn_sched_barrier(0);
  __builtin_amdgcn_s_barrier();

  for (int tt = 0; tt < NT; ++tt) {
    const int cur = tt & 1;
    const bf16* bufA = &lds[cur][0];
    const bf16* bufB = &lds[cur][16384];
    bf16x8 b0[4], b1[4];

    { // P1: mh=0, kk=0
      bf16x8 a[4];
      #pragma unroll
      for (int n = 0; n < 4; ++n) b0[n] = *(const bf16x8*)(bufB + brow + n * 1024 + fcol0);
      #pragma unroll
      for (int mi = 0; mi < 4; ++mi) a[mi] = *(const bf16x8*)(bufA + arow + mi * 1024 + fcol0);
      if (tt + 1 < NT) { STAGE(cur ^ 1, true, 128, tt + 1); STAGE(cur ^ 1, true, 192, tt + 1); }
      __builtin_amdgcn_s_barrier();
      asm volatile("s_waitcnt lgkmcnt(0)" ::: "memory");
      __builtin_amdgcn_sched_barrier(0);
      __builtin_amdgcn_s_setprio(1);
      #pragma unroll
      for (int mi = 0; mi < 4; ++mi)
        #pragma unroll
        for (int n = 0; n < 4; ++n)
          acc[mi][n] = __builtin_amdgcn_mfma_f32_16x16x32_bf16(a[mi], b0[n], acc[mi][n], 0, 0, 0);
      __builtin_amdgcn_s_setprio(0);
      __builtin_amdgcn_s_barrier();
    }
    { // P2: mh=0, kk=1
      bf16x8 a[4];
      #pragma unroll
      for (int n = 0; n < 4; ++n) b1[n] = *(const bf16x8*)(bufB + brow + n * 1024 + fcol1);
      #pragma unroll
      for (int mi = 0; mi < 4; ++mi) a[mi] = *(const bf16x8*)(bufA + arow + mi * 1024 + fcol1);
      if (tt + 1 < NT) { STAGE(cur ^ 1, false, 64, tt + 1); STAGE(cur ^ 1, false, 192, tt + 1); }
      __builtin_amdgcn_s_barrier();
      asm volatile("s_waitcnt lgkmcnt(0)" ::: "memory");
      __builtin_amdgcn_sched_barrier(0);
      __builtin_amdgcn_s_setprio(1);
      #pragma unroll
      for (int mi = 0; mi < 4; ++mi)
        #pragma unroll
        for (int n = 0; n < 4; ++n)
          acc[mi][n] = __builtin_amdgcn_mfma_f32_16x16x32_bf16(a[mi], b1[n], acc[mi][n], 0, 0, 0);
      __builtin_amdgcn_s_setprio(0);
      __builtin_amdgcn_s_barrier();
    }
    { // P3: mh=1, kk=0
      bf16x8 a[4];
      #pragma unroll
      for (int mi = 0; mi < 4; ++mi) a[mi] = *(const bf16x8*)(bufA + arow + 4096 + mi * 1024 + fcol0);
      if (tt + 2 < NT) { STAGE(cur, false, 0, tt + 2); STAGE(cur, false, 128, tt + 2); }
      __builtin_amdgcn_s_barrier();
      asm volatile("s_waitcnt lgkmcnt(0)" ::: "memory");
      __builtin_amdgcn_sched_barrier(0);
      __builtin_amdgcn_s_setprio(1);
      #pragma unroll
      for (int mi = 0; mi < 4; ++mi)
        #pragma unroll
        for (int n = 0; n < 4; ++n)
          acc[4 + mi][n] = __builtin_amdgcn_mfma_f32_16x16x32_bf16(a[mi], b0[n], acc[4 + mi][n], 0, 0, 0);
      __builtin_amdgcn_s_setprio(0);
      __builtin_amdgcn_s_barrier();
    }
    { // P4: mh=1, kk=1
      bf16x8 a[4];
      #pragma unroll
      for (int mi = 0; mi < 4; ++mi) a[mi] = *(const bf16x8*)(bufA + arow + 4096 + mi * 1024 + fcol1);
      if (tt + 2 < NT) { STAGE(cur, true, 0, tt + 2); STAGE(cur, true, 64, tt + 2); }
      __builtin_amdgcn_s_barrier();
      asm volatile("s_waitcnt lgkmcnt(0)" ::: "memory");
      __builtin_amdgcn_sched_barrier(0);
      __builtin_amdgcn_s_setprio(1);
      #pragma unroll
      for (int mi = 0; mi < 4; ++mi)
        #pragma unroll
        for (int n = 0; n < 4; ++n)
          acc[4 + mi][n] = __builtin_amdgcn_mfma_f32_16x16x32_bf16(a[mi], b1[n], acc[4 + mi][n], 0, 0, 0);
      __builtin_amdgcn_s_setprio(0);
      if (tt + 2 < NT) { asm volatile("s_waitcnt vmcnt(4)" ::: "memory"); }
      else             { asm volatile("s_waitcnt vmcnt(0)" ::: "memory"); }
      __builtin_amdgcn_sched_barrier(0);
      __builtin_amdgcn_s_barrier();
    }
  }
#undef STAGE

  // ======== LDS-transposed epilogue: coalesced stores ========
  float* Lf = (float*)&lds[0][0];   // 32768 f32 = 128 KiB

  float bN[4];
  if (EPI == 5) {
    #pragma unroll
    for (int n = 0; n < 4; ++n) bN[n] = biasU[bn + wc * 64 + n * 16 + lr];
  }

  #pragma unroll
  for (int h = 0; h < 2; ++h) {
    if (wr == h) {
      #pragma unroll
      for (int m = 0; m < 8; ++m)
        #pragma unroll
        for (int n = 0; n < 4; ++n)
          #pragma unroll
          for (int e = 0; e < 4; ++e) {
            const int lrow = kg * 4 + m * 16 + e;          // 0..127
            const int lcol = wc * 64 + n * 16 + lr;        // 0..255
            float v = acc[m][n][e];
            if (EPI == 2 || EPI == 4) v = 1.0f / (1.0f + __expf(-v * scale));
            if (EPI == 5) v += bN[n];
            Lf[lrow * 256 + (lcol ^ (((lrow >> 2) & 3) << 4))] = v;
          }
    }
    __syncthreads();
    #pragma unroll
    for (int rr = 0; rr < 16; ++rr) {
      const int lrow = wid * 16 + rr;
      const int cb   = lane * 4;                            // 0..252
      const int cbs  = cb ^ (((lrow >> 2) & 3) << 4);
      const f32x4 v  = *(const f32x4*)&Lf[lrow * 256 + cbs];
      const int gr   = bm + h * 128 + lrow;
      const int gc   = bn + cb;
      if (EPI == 2 || EPI == 4) {
        __builtin_nontemporal_store(v, (f32x4*)&CfU[(size_t)gr * N + gc]);
        if (EPI == 4) {
          ushort4 p; p.x = f2b(v[0]); p.y = f2b(v[1]); p.z = f2b(v[2]); p.w = f2b(v[3]);
          *(ushort4*)&CbU[(size_t)gr * N + gc] = p;
        }
      } else if (EPI == 3) {
        __builtin_nontemporal_store(v, (f32x4*)&CfU[(size_t)gr * N + gc]);
      } else if (EPI == 5) {
        const int seg = bn >> 10;              // 0=q 1=k 2=v (block-uniform; 256|1024)
        const int cl  = (bn & 1023) + cb;
        const int r   = bmL + h * 128 + lrow;
        bf16* sel = (seg == 0) ? CqU : (seg == 1) ? CkU : CvU;
        ushort4 p; p.x = f2b(v[0]); p.y = f2b(v[1]); p.z = f2b(v[2]); p.w = f2b(v[3]);
        *(ushort4*)&sel[(size_t)r * DIM + cl] = p;
      }
    }
    __syncthreads();
  }
}

// ================= legacy 128x128 GEMM (low-ws fallback only) =================
template<int EPI, bool A_F32>
__global__ __launch_bounds__(256) void gemm_nt(
    const void* __restrict__ Ap, const bf16* __restrict__ Bt,
    int M, int N, int K,
    float scale, float* __restrict__ Cf)
{
  __shared__ bf16 As[128 * 32];
  __shared__ bf16 Bs[128 * 32];
  const int tid  = threadIdx.x;
  const int lane = tid & 63, wid = tid >> 6;
  const int wrr = wid >> 1, wcc = wid & 1;
  const int tilesN = N >> 7;
  const int nwg = gridDim.x;
  int bid = blockIdx.x;
  if ((nwg & 7) == 0) { const int q = nwg >> 3; bid = (bid & 7) * q + (bid >> 3); }
  const int bm = (bid / tilesN) * 128, bn = (bid % tilesN) * 128;
  f32x4 acc[4][4] = {};
  const bf16*  Ab16 = (const bf16*)Ap;
  const float* Af32 = (const float*)Ap;
  const int srow = tid >> 2, sc8 = (tid & 3) * 8;
  const int frow = tid >> 3, fc4 = (tid & 7) * 4;

  for (int k0 = 0; k0 < K; k0 += 32) {
    if (A_F32) {
      #pragma unroll
      for (int is = 0; is < 4; ++is) {
        int row = is * 32 + frow;
        const float4 v = *(const float4*)(Af32 + (size_t)(bm + row) * K + k0 + fc4);
        ushort4 p; p.x = f2b(v.x); p.y = f2b(v.y); p.z = f2b(v.z); p.w = f2b(v.w);
        *(ushort4*)(&As[row * 32 + fc4]) = p;
      }
    } else {
      #pragma unroll
      for (int is = 0; is < 2; ++is) {
        int row = is * 64 + srow;
        const bf16* g = Ab16 + (size_t)(bm + row) * K + k0 + sc8;
        __builtin_amdgcn_global_load_lds(
            (const __attribute__((address_space(1))) unsigned int*)g,
            (__attribute__((address_space(3))) unsigned int*)(&As[row * 32 + sc8]), 16, 0, 0);
      }
    }
    #pragma unroll
    for (int is = 0; is < 2; ++is) {
      int row = is * 64 + srow;
      const bf16* g = Bt + (size_t)(bn + row) * K + k0 + sc8;
      __builtin_amdgcn_global_load_lds(
          (const __attribute__((address_space(1))) unsigned int*)g,
          (__attribute__((address_space(3))) unsigned int*)(&Bs[row * 32 + sc8]), 16, 0, 0);
    }
    __syncthreads();
    const int lrr = lane & 15, kgg = lane >> 4;
    bf16x8 af[4], bfv[4];
    #pragma unroll
    for (int i = 0; i < 4; ++i)
      af[i] = *(const bf16x8*)(&As[(wrr * 64 + i * 16 + lrr) * 32 + kgg * 8]);
    #pragma unroll
    for (int j = 0; j < 4; ++j)
      bfv[j] = *(const bf16x8*)(&Bs[(wcc * 64 + j * 16 + lrr) * 32 + kgg * 8]);
    #pragma unroll
    for (int i = 0; i < 4; ++i)
      #pragma unroll
      for (int j = 0; j < 4; ++j)
        acc[i][j] = __builtin_amdgcn_mfma_f32_16x16x32_bf16(af[i], bfv[j], acc[i][j], 0, 0, 0);
    __syncthreads();
  }
  const int r0 = bm + wrr * 64 + (lane >> 4) * 4;
  const int c0 = bn + wcc * 64 + (lane & 15);
  if (EPI == 2) {
    #pragma unroll
    for (int i = 0; i < 4; ++i)
      #pragma unroll
      for (int j = 0; j < 4; ++j)
        #pragma unroll
        for (int e = 0; e < 4; ++e) {
          float pr = 1.0f / (1.0f + __expf(-acc[i][j][e] * scale));
          Cf[(size_t)(r0 + i * 16 + e) * N + c0 + j * 16] = pr;
        }
  } else {
    #pragma unroll
    for (int i = 0; i < 4; ++i)
      #pragma unroll
      for (int j = 0; j < 4; ++j)
        #pragma unroll
        for (int e = 0; e < 4; ++e)
          Cf[(size_t)(r0 + i * 16 + e) * N + c0 + j * 16] = acc[i][j][e];
  }
}

extern "C" void kernel_launch(void* const* d_in, const int* in_sizes, int n_in,
                              void* d_out, int out_size, void* d_ws, size_t ws_size,
                              hipStream_t stream) {
  const float* x1 = (const float*)d_in[0];
  const float* x2 = (const float*)d_in[1];
  const float* W[6] = { (const float*)d_in[2],  (const float*)d_in[4],  (const float*)d_in[6],
                        (const float*)d_in[8],  (const float*)d_in[10], (const float*)d_in[12] };
  const float* B[6] = { (const float*)d_in[3],  (const float*)d_in[5],  (const float*)d_in[7],
                        (const float*)d_in[9],  (const float*)d_in[11], (const float*)d_in[13] };

  const size_t MD = (size_t)NTOK * DIM;
  const size_t DD = (size_t)DIM * DIM;
  const size_t NN = (size_t)NTOK * NTOK;

  bf16* ws   = (bf16*)d_ws;
  bf16* x1b  = ws;                         // contiguous with x2b -> proj A (16384 rows)
  bf16* x2b  = x1b + MD;
  bf16* wt1  = x2b + MD;
  bf16* wt2  = wt1 + 3 * DD;
  float* bstack = (float*)(wt2 + 3 * DD);  // 6144 f32 in 16384-bf16 slot
  bf16* q1   = wt2 + 3 * DD + 16384;
  bf16* k1   = q1 + MD;
  bf16* q2   = k1 + MD;
  bf16* k2   = q2 + MD;
  bf16* v1r  = k2 + MD;
  bf16* v2r  = v1r + MD;
  bf16* v1T  = v2r + MD;
  bf16* v2T  = v1T + MD;
  bf16* probsb = v2T + MD;                 // 2 x 64M bf16

  const size_t topBytes = ((size_t)(10 * MD + 6 * DD + 16384) + 2 * NN) * 2;
  const bool top = (ws_size >= topBytes);  // ~440 MB; measured ws ≈ 2.4 GB

  float* out    = (float*)d_out;
  float* ctx2   = out;
  float* probs2 = ctx2 + MD;
  float* ctx1   = probs2 + NN;
  float* probs1 = ctx1 + MD;

  const float scale = 1.0f / 32.0f;

  // merged pre-passes: 1 cast dispatch + 1 weight-transpose dispatch + bias pack
  {
    int n4 = (int)(MD / 4);
    cast2_f32_bf16<<<(2 * n4 + 255) / 256, 256, 0, stream>>>(x1, x2, x1b, n4);
  }
  transpose_cast6<<<6 * (DIM / 32) * (DIM / 32), 256, 0, stream>>>(
      W[0], W[1], W[2], W[3], W[4], W[5], wt1);
  pack_bias<<<24, 256, 0, stream>>>(B[0], B[1], B[2], B[3], B[4], B[5], bstack);

  // fused QKV projection: A = [x1b;x2b] (16384 x 1024), N = 3072. grid 768.
  gemm256<5, false><<<64 * 12, 512, 0, stream>>>(
      x1b, wt1, nullptr, wt2, 2 * NTOK, 3 * DIM, DIM, 12, 768,
      bstack, bstack + 3 * DIM, 0.f,
      nullptr, nullptr, nullptr, nullptr,
      q1, k1, v1r, q2, k2, v2r);

  // v transpose: [8192,1024] -> [1024,8192], both inputs
  transpose_bf16<<<2 * (NTOK / 64) * (DIM / 64), 256, 0, stream>>>(
      (const short*)v1r, (short*)v1T, (const short*)v2r, (short*)v2T, NTOK, DIM);

  const int perQK = (NTOK / 256) * (NTOK / 256);  // 1024
  const int perPV = (NTOK / 256) * (DIM / 256);   // 128

  if (top) {
    // fused dual QK: dir0 probs2 = sig(s*q1@k2^T) -> f32+bf16; dir1 likewise. 2048 blocks.
    gemm256<4, true><<<2 * perQK, 512, 0, stream>>>(
        q1, k2, q2, k1, NTOK, NTOK, DIM, 32, perQK,
        nullptr, nullptr, scale,
        probs2, probs1, probsb, probsb + NN,
        nullptr, nullptr, nullptr, nullptr, nullptr, nullptr);
    // fused dual PV: ctx2 = probsb@v2, ctx1 = probsb'@v1. K=8192, NT=128. 256 blocks = 1/CU.
    gemm256<3, true><<<2 * perPV, 512, 0, stream>>>(
        probsb, v2T, probsb + NN, v1T, NTOK, DIM, NTOK, 4, perPV,
        nullptr, nullptr, 0.f,
        ctx2, ctx1, nullptr, nullptr,
        nullptr, nullptr, nullptr, nullptr, nullptr, nullptr);
  } else {
    // fallback: f32 probs only; PV re-reads f32 probs from d_out with convert-on-stage
    gemm256<2, false><<<perQK, 512, 0, stream>>>(
        q1, k2, nullptr, nullptr, NTOK, NTOK, DIM, 32, perQK,
        nullptr, nullptr, scale,
        probs2, nullptr, nullptr, nullptr,
        nullptr, nullptr, nullptr, nullptr, nullptr, nullptr);
    gemm_nt<3, true><<<(NTOK / 128) * (DIM / 128), 256, 0, stream>>>(
        probs2, v2T, NTOK, DIM, NTOK, 0.f, ctx2);
    gemm256<2, false><<<perQK, 512, 0, stream>>>(
        q2, k1, nullptr, nullptr, NTOK, NTOK, DIM, 32, perQK,
        nullptr, nullptr, scale,
        probs1, nullptr, nullptr, nullptr,
        nullptr, nullptr, nullptr, nullptr, nullptr, nullptr);
    gemm_nt<3, true><<<(NTOK / 128) * (DIM / 128), 256, 0, stream>>>(
        probs1, v1T, NTOK, DIM, NTOK, 0.f, ctx1);
  }
}

// Round 15
// 768.044 us; speedup vs baseline: 1.1861x; 1.0093x over previous
//
#include <hip/hip_runtime.h>
#include <hip/hip_bf16.h>

#define DIM   1024
#define NTOK  8192

using bf16 = __hip_bfloat16;
typedef __attribute__((ext_vector_type(8))) short bf16x8;
typedef __attribute__((ext_vector_type(4))) float f32x4;

__device__ __forceinline__ unsigned short f2b(float x) {
  union { __hip_bfloat16 h; unsigned short u; } cv;
  cv.h = __float2bfloat16(x);
  return cv.u;
}

// ---------------- cast f32 -> bf16, dual-source single dispatch ----------------
__global__ __launch_bounds__(256) void cast2_f32_bf16(const float* __restrict__ in0,
                                                      const float* __restrict__ in1,
                                                      bf16* __restrict__ out, int n4) {
  int i = blockIdx.x * 256 + threadIdx.x;
  if (i < 2 * n4) {
    const float* src = (i < n4) ? in0 : in1;
    int j = (i < n4) ? i : i - n4;
    const float4 v = ((const float4*)src)[j];
    ushort4 p;
    p.x = f2b(v.x); p.y = f2b(v.y); p.z = f2b(v.z); p.w = f2b(v.w);
    ((ushort4*)out)[i] = p;
  }
}

// ------ tiled transpose + cast for 6 DxD weights in one dispatch ------
__global__ __launch_bounds__(256) void transpose_cast6(
    const float* __restrict__ w0, const float* __restrict__ w1,
    const float* __restrict__ w2, const float* __restrict__ w3,
    const float* __restrict__ w4, const float* __restrict__ w5,
    bf16* __restrict__ base) {
  __shared__ float t[32][33];
  const int tilesC = DIM / 32;
  const int blksPerW = tilesC * (DIM / 32);
  const int widx = blockIdx.x / blksPerW;
  const int lb   = blockIdx.x % blksPerW;
  const float* in = (widx == 0) ? w0 : (widx == 1) ? w1 : (widx == 2) ? w2
                   : (widx == 3) ? w3 : (widx == 4) ? w4 : w5;
  bf16* out = base + (size_t)widx * DIM * DIM;
  const int c0 = (lb % tilesC) * 32;
  const int r0 = (lb / tilesC) * 32;
  const int tx = threadIdx.x & 31, ty = threadIdx.x >> 5;
  #pragma unroll
  for (int i = 0; i < 4; ++i) {
    int r = ty + i * 8;
    t[r][tx] = in[(size_t)(r0 + r) * DIM + c0 + tx];
  }
  __syncthreads();
  #pragma unroll
  for (int i = 0; i < 4; ++i) {
    int cr = ty + i * 8;
    out[(size_t)(c0 + cr) * DIM + r0 + tx] = __float2bfloat16(t[tx][cr]);
  }
}

// ------------- bf16 transpose, 64x64 tiles, vectorized both sides, dual-input -------------
__global__ __launch_bounds__(256) void transpose_bf16(const short* __restrict__ in,
                                                      short* __restrict__ out,
                                                      const short* __restrict__ in2,
                                                      short* __restrict__ out2,
                                                      int R, int C) {
  __shared__ short t[64][72];
  const int tilesC = C >> 6;
  const int tilesPer = (R >> 6) * tilesC;
  int bid = blockIdx.x;
  const short* src = in; short* dst = out;
  if (bid >= tilesPer) { bid -= tilesPer; src = in2; dst = out2; }
  const int r0 = (bid / tilesC) << 6, c0 = (bid % tilesC) << 6;
  const int tr = threadIdx.x >> 3, tc8 = (threadIdx.x & 7) << 3;
  #pragma unroll
  for (int p = 0; p < 2; ++p) {
    int r = tr + p * 32;
    int sc = tc8 ^ (((r >> 3) & 7) << 3);
    *(bf16x8*)&t[r][sc] = *(const bf16x8*)&src[(size_t)(r0 + r) * C + c0 + tc8];
  }
  __syncthreads();
  #pragma unroll
  for (int p = 0; p < 2; ++p) {
    int oc = tr + p * 32;
    bf16x8 v;
    #pragma unroll
    for (int e = 0; e < 8; ++e) {
      int a = tc8 + e;
      v[e] = t[a][oc ^ (((a >> 3) & 7) << 3)];
    }
    *(bf16x8*)&dst[(size_t)(c0 + oc) * R + r0 + tc8] = v;
  }
}

// ---------------- pack 6 bias vectors ----------------
__global__ __launch_bounds__(256) void pack_bias(const float* b0, const float* b1,
                                                 const float* b2, const float* b3,
                                                 const float* b4, const float* b5,
                                                 float* __restrict__ out) {
  int i = blockIdx.x * 256 + threadIdx.x;
  if (i < 6 * DIM) {
    int s = i >> 10, o = i & 1023;
    const float* p = (s == 0) ? b0 : (s == 1) ? b1 : (s == 2) ? b2 : (s == 3) ? b3 : (s == 4) ? b4 : b5;
    out[i] = p[o];
  }
}

// ================= 256x256 8-phase NT GEMM (r9 structure, best measured) =================
// MMAJ (PV only): XCD-owns-m-row mapping — bid -> ((xcd*8 + j>>2)*4 + (j&3)) so all
// 4 n-tiles sharing one 4MB probs A-panel run back-to-back on ONE XCD (panel fits
// its 4MB L2 -> A-refetch 4x -> 1x). Default mapping: bijective XCD swizzle.
// EPI: 2 = sigmoid->f32 | 3 = f32 | 4 = sigmoid->f32+bf16 | 5 = fused QKV proj
template<int EPI, bool DUAL, bool MMAJ>
__global__ __launch_bounds__(512, 1) void gemm256(
    const bf16* __restrict__ A,  const bf16* __restrict__ Bt,
    const bf16* __restrict__ A2, const bf16* __restrict__ Bt2,
    int M, int N, int K, int tilesN, int perDir,
    const float* __restrict__ bias, const float* __restrict__ bias2, float scale,
    float* __restrict__ Cf, float* __restrict__ Cf2,
    bf16* __restrict__ Cb, bf16* __restrict__ Cb2,
    bf16* __restrict__ Cq, bf16* __restrict__ Ck, bf16* __restrict__ Cv,
    bf16* __restrict__ Cq2, bf16* __restrict__ Ck2, bf16* __restrict__ Cv2)
{
  __shared__ bf16 lds[2][2 * 16384];
  const int t    = threadIdx.x;
  const int lane = t & 63, wid = t >> 6;
  const int wr = wid >> 2, wc = wid & 3;
  const int lr = lane & 15, kg = lane >> 4;

  int bid = blockIdx.x;
  if (MMAJ) {
    // PV: grid 256, tilesN=4. XCD x owns m-units {x*8 .. x*8+7}, 4 n-tiles each.
    const int xcd = bid & 7, j = bid >> 3;
    bid = (xcd * 8 + (j >> 2)) * 4 + (j & 3);
  } else {
    const int nwg = gridDim.x;
    const int q = nwg >> 3;
    bid = (bid & 7) * q + (bid >> 3);
  }

  const bf16* Au = A; const bf16* BtU = Bt;
  float* CfU = Cf; bf16* CbU = Cb;
  if (DUAL && bid >= perDir) { bid -= perDir; Au = A2; BtU = Bt2; CfU = Cf2; CbU = Cb2; }

  const int bm = (bid / tilesN) << 8;
  const int bn = (bid % tilesN) << 8;

  // proj: dual-by-row select
  const float* biasU = bias;
  bf16 *CqU = Cq, *CkU = Ck, *CvU = Cv;
  int bmL = bm;
  if (EPI == 5 && bm >= (M >> 1)) {
    BtU = Bt2; biasU = bias2; CqU = Cq2; CkU = Ck2; CvU = Cv2; bmL = bm - (M >> 1);
  }

  // staging: thread t covers one 16B chunk of each 64-row region; source col pre-swizzled
  const int srow = t >> 3;
  const int scol = ((t & 7) ^ (srow & 7)) * 8;
  const size_t bA = (size_t)(bm + srow) * K + scol;
  const size_t bB = (size_t)(bn + srow) * K + scol;

#define STAGE(buf, isB, R0, tt_) do {                                                   \
    const bf16* g_ = ((isB) ? BtU + bB : Au + bA) + (size_t)(R0) * K + (size_t)(tt_) * 64; \
    __builtin_amdgcn_global_load_lds(                                                   \
        (const __attribute__((address_space(1))) unsigned int*)g_,                      \
        (__attribute__((address_space(3))) unsigned int*)(&lds[buf][((isB) ? 16384 : 0) + (R0) * 64 + t * 8]), \
        16, 0, 0);                                                                      \
  } while (0)

  // fragment read offsets (swizzled): col16 = (kk*4+kg) ^ (lr&7)
  const int fcol0 = ((kg)     ^ (lr & 7)) * 8;
  const int fcol1 = ((4 + kg) ^ (lr & 7)) * 8;
  const int arow = (wr * 128 + lr) * 64;
  const int brow = (wc * 64 + lr) * 64;

  f32x4 acc[8][4] = {};
  const int NT = K >> 6;

  // ---- prologue: tile0 full -> buf0; tile1 half -> buf1 ----
  STAGE(0, false, 0, 0);   STAGE(0, false, 128, 0);
  STAGE(0, false, 64, 0);  STAGE(0, false, 192, 0);
  STAGE(0, true, 0, 0);    STAGE(0, true, 64, 0);
  STAGE(0, true, 128, 0);  STAGE(0, true, 192, 0);
  if (NT > 1) {
    STAGE(1, false, 0, 1); STAGE(1, false, 128, 1);
    STAGE(1, true, 0, 1);  STAGE(1, true, 64, 1);
    asm volatile("s_waitcnt vmcnt(4)" ::: "memory");
  } else {
    asm volatile("s_waitcnt vmcnt(0)" ::: "memory");
  }
  __builtin_amdgcn_sched_barrier(0);
  __builtin_amdgcn_s_barrier();

  for (int tt = 0; tt < NT; ++tt) {
    const int cur = tt & 1;
    const bf16* bufA = &lds[cur][0];
    const bf16* bufB = &lds[cur][16384];
    bf16x8 b0[4], b1[4];

    { // P1: mh=0, kk=0
      bf16x8 a[4];
      #pragma unroll
      for (int n = 0; n < 4; ++n) b0[n] = *(const bf16x8*)(bufB + brow + n * 1024 + fcol0);
      #pragma unroll
      for (int mi = 0; mi < 4; ++mi) a[mi] = *(const bf16x8*)(bufA + arow + mi * 1024 + fcol0);
      if (tt + 1 < NT) { STAGE(cur ^ 1, true, 128, tt + 1); STAGE(cur ^ 1, true, 192, tt + 1); }
      __builtin_amdgcn_s_barrier();
      asm volatile("s_waitcnt lgkmcnt(0)" ::: "memory");
      __builtin_amdgcn_sched_barrier(0);
      __builtin_amdgcn_s_setprio(1);
      #pragma unroll
      for (int mi = 0; mi < 4; ++mi)
        #pragma unroll
        for (int n = 0; n < 4; ++n)
          acc[mi][n] = __builtin_amdgcn_mfma_f32_16x16x32_bf16(a[mi], b0[n], acc[mi][n], 0, 0, 0);
      __builtin_amdgcn_s_setprio(0);
      __builtin_amdgcn_s_barrier();
    }
    { // P2: mh=0, kk=1
      bf16x8 a[4];
      #pragma unroll
      for (int n = 0; n < 4; ++n) b1[n] = *(const bf16x8*)(bufB + brow + n * 1024 + fcol1);
      #pragma unroll
      for (int mi = 0; mi < 4; ++mi) a[mi] = *(const bf16x8*)(bufA + arow + mi * 1024 + fcol1);
      if (tt + 1 < NT) { STAGE(cur ^ 1, false, 64, tt + 1); STAGE(cur ^ 1, false, 192, tt + 1); }
      __builtin_amdgcn_s_barrier();
      asm volatile("s_waitcnt lgkmcnt(0)" ::: "memory");
      __builtin_amdgcn_sched_barrier(0);
      __builtin_amdgcn_s_setprio(1);
      #pragma unroll
      for (int mi = 0; mi < 4; ++mi)
        #pragma unroll
        for (int n = 0; n < 4; ++n)
          acc[mi][n] = __builtin_amdgcn_mfma_f32_16x16x32_bf16(a[mi], b1[n], acc[mi][n], 0, 0, 0);
      __builtin_amdgcn_s_setprio(0);
      __builtin_amdgcn_s_barrier();
    }
    { // P3: mh=1, kk=0
      bf16x8 a[4];
      #pragma unroll
      for (int mi = 0; mi < 4; ++mi) a[mi] = *(const bf16x8*)(bufA + arow + 4096 + mi * 1024 + fcol0);
      if (tt + 2 < NT) { STAGE(cur, false, 0, tt + 2); STAGE(cur, false, 128, tt + 2); }
      __builtin_amdgcn_s_barrier();
      asm volatile("s_waitcnt lgkmcnt(0)" ::: "memory");
      __builtin_amdgcn_sched_barrier(0);
      __builtin_amdgcn_s_setprio(1);
      #pragma unroll
      for (int mi = 0; mi < 4; ++mi)
        #pragma unroll
        for (int n = 0; n < 4; ++n)
          acc[4 + mi][n] = __builtin_amdgcn_mfma_f32_16x16x32_bf16(a[mi], b0[n], acc[4 + mi][n], 0, 0, 0);
      __builtin_amdgcn_s_setprio(0);
      __builtin_amdgcn_s_barrier();
    }
    { // P4: mh=1, kk=1
      bf16x8 a[4];
      #pragma unroll
      for (int mi = 0; mi < 4; ++mi) a[mi] = *(const bf16x8*)(bufA + arow + 4096 + mi * 1024 + fcol1);
      if (tt + 2 < NT) { STAGE(cur, true, 0, tt + 2); STAGE(cur, true, 64, tt + 2); }
      __builtin_amdgcn_s_barrier();
      asm volatile("s_waitcnt lgkmcnt(0)" ::: "memory");
      __builtin_amdgcn_sched_barrier(0);
      __builtin_amdgcn_s_setprio(1);
      #pragma unroll
      for (int mi = 0; mi < 4; ++mi)
        #pragma unroll
        for (int n = 0; n < 4; ++n)
          acc[4 + mi][n] = __builtin_amdgcn_mfma_f32_16x16x32_bf16(a[mi], b1[n], acc[4 + mi][n], 0, 0, 0);
      __builtin_amdgcn_s_setprio(0);
      if (tt + 2 < NT) { asm volatile("s_waitcnt vmcnt(4)" ::: "memory"); }
      else             { asm volatile("s_waitcnt vmcnt(0)" ::: "memory"); }
      __builtin_amdgcn_sched_barrier(0);
      __builtin_amdgcn_s_barrier();
    }
  }
#undef STAGE

  // ======== LDS-transposed epilogue: coalesced stores ========
  float* Lf = (float*)&lds[0][0];

  float bN[4];
  if (EPI == 5) {
    #pragma unroll
    for (int n = 0; n < 4; ++n) bN[n] = biasU[bn + wc * 64 + n * 16 + lr];
  }

  #pragma unroll
  for (int h = 0; h < 2; ++h) {
    if (wr == h) {
      #pragma unroll
      for (int m = 0; m < 8; ++m)
        #pragma unroll
        for (int n = 0; n < 4; ++n)
          #pragma unroll
          for (int e = 0; e < 4; ++e) {
            const int lrow = kg * 4 + m * 16 + e;
            const int lcol = wc * 64 + n * 16 + lr;
            float v = acc[m][n][e];
            if (EPI == 2 || EPI == 4) v = 1.0f / (1.0f + __expf(-v * scale));
            if (EPI == 5) v += bN[n];
            Lf[lrow * 256 + (lcol ^ (((lrow >> 2) & 3) << 4))] = v;
          }
    }
    __syncthreads();
    #pragma unroll
    for (int rr = 0; rr < 16; ++rr) {
      const int lrow = wid * 16 + rr;
      const int cb   = lane * 4;
      const int cbs  = cb ^ (((lrow >> 2) & 3) << 4);
      const f32x4 v  = *(const f32x4*)&Lf[lrow * 256 + cbs];
      const int gr   = bm + h * 128 + lrow;
      const int gc   = bn + cb;
      if (EPI == 2 || EPI == 4) {
        __builtin_nontemporal_store(v, (f32x4*)&CfU[(size_t)gr * N + gc]);
        if (EPI == 4) {
          ushort4 p; p.x = f2b(v[0]); p.y = f2b(v[1]); p.z = f2b(v[2]); p.w = f2b(v[3]);
          *(ushort4*)&CbU[(size_t)gr * N + gc] = p;
        }
      } else if (EPI == 3) {
        __builtin_nontemporal_store(v, (f32x4*)&CfU[(size_t)gr * N + gc]);
      } else if (EPI == 5) {
        const int seg = bn >> 10;
        const int cl  = (bn & 1023) + cb;
        const int r   = bmL + h * 128 + lrow;
        bf16* sel = (seg == 0) ? CqU : (seg == 1) ? CkU : CvU;
        ushort4 p; p.x = f2b(v[0]); p.y = f2b(v[1]); p.z = f2b(v[2]); p.w = f2b(v[3]);
        *(ushort4*)&sel[(size_t)r * DIM + cl] = p;
      }
    }
    __syncthreads();
  }
}

// ================= legacy 128x128 GEMM (low-ws fallback only) =================
template<int EPI, bool A_F32>
__global__ __launch_bounds__(256) void gemm_nt(
    const void* __restrict__ Ap, const bf16* __restrict__ Bt,
    int M, int N, int K,
    float scale, float* __restrict__ Cf)
{
  __shared__ bf16 As[128 * 32];
  __shared__ bf16 Bs[128 * 32];
  const int tid  = threadIdx.x;
  const int lane = tid & 63, wid = tid >> 6;
  const int wrr = wid >> 1, wcc = wid & 1;
  const int tilesN = N >> 7;
  const int nwg = gridDim.x;
  int bid = blockIdx.x;
  if ((nwg & 7) == 0) { const int q = nwg >> 3; bid = (bid & 7) * q + (bid >> 3); }
  const int bm = (bid / tilesN) * 128, bn = (bid % tilesN) * 128;
  f32x4 acc[4][4] = {};
  const bf16*  Ab16 = (const bf16*)Ap;
  const float* Af32 = (const float*)Ap;
  const int srow = tid >> 2, sc8 = (tid & 3) * 8;
  const int frow = tid >> 3, fc4 = (tid & 7) * 4;

  for (int k0 = 0; k0 < K; k0 += 32) {
    if (A_F32) {
      #pragma unroll
      for (int is = 0; is < 4; ++is) {
        int row = is * 32 + frow;
        const float4 v = *(const float4*)(Af32 + (size_t)(bm + row) * K + k0 + fc4);
        ushort4 p; p.x = f2b(v.x); p.y = f2b(v.y); p.z = f2b(v.z); p.w = f2b(v.w);
        *(ushort4*)(&As[row * 32 + fc4]) = p;
      }
    } else {
      #pragma unroll
      for (int is = 0; is < 2; ++is) {
        int row = is * 64 + srow;
        const bf16* g = Ab16 + (size_t)(bm + row) * K + k0 + sc8;
        __builtin_amdgcn_global_load_lds(
            (const __attribute__((address_space(1))) unsigned int*)g,
            (__attribute__((address_space(3))) unsigned int*)(&As[row * 32 + sc8]), 16, 0, 0);
      }
    }
    #pragma unroll
    for (int is = 0; is < 2; ++is) {
      int row = is * 64 + srow;
      const bf16* g = Bt + (size_t)(bn + row) * K + k0 + sc8;
      __builtin_amdgcn_global_load_lds(
          (const __attribute__((address_space(1))) unsigned int*)g,
          (__attribute__((address_space(3))) unsigned int*)(&Bs[row * 32 + sc8]), 16, 0, 0);
    }
    __syncthreads();
    const int lrr = lane & 15, kgg = lane >> 4;
    bf16x8 af[4], bfv[4];
    #pragma unroll
    for (int i = 0; i < 4; ++i)
      af[i] = *(const bf16x8*)(&As[(wrr * 64 + i * 16 + lrr) * 32 + kgg * 8]);
    #pragma unroll
    for (int j = 0; j < 4; ++j)
      bfv[j] = *(const bf16x8*)(&Bs[(wcc * 64 + j * 16 + lrr) * 32 + kgg * 8]);
    #pragma unroll
    for (int i = 0; i < 4; ++i)
      #pragma unroll
      for (int j = 0; j < 4; ++j)
        acc[i][j] = __builtin_amdgcn_mfma_f32_16x16x32_bf16(af[i], bfv[j], acc[i][j], 0, 0, 0);
    __syncthreads();
  }
  const int r0 = bm + wrr * 64 + (lane >> 4) * 4;
  const int c0 = bn + wcc * 64 + (lane & 15);
  if (EPI == 2) {
    #pragma unroll
    for (int i = 0; i < 4; ++i)
      #pragma unroll
      for (int j = 0; j < 4; ++j)
        #pragma unroll
        for (int e = 0; e < 4; ++e) {
          float pr = 1.0f / (1.0f + __expf(-acc[i][j][e] * scale));
          Cf[(size_t)(r0 + i * 16 + e) * N + c0 + j * 16] = pr;
        }
  } else {
    #pragma unroll
    for (int i = 0; i < 4; ++i)
      #pragma unroll
      for (int j = 0; j < 4; ++j)
        #pragma unroll
        for (int e = 0; e < 4; ++e)
          Cf[(size_t)(r0 + i * 16 + e) * N + c0 + j * 16] = acc[i][j][e];
  }
}

extern "C" void kernel_launch(void* const* d_in, const int* in_sizes, int n_in,
                              void* d_out, int out_size, void* d_ws, size_t ws_size,
                              hipStream_t stream) {
  const float* x1 = (const float*)d_in[0];
  const float* x2 = (const float*)d_in[1];
  const float* W[6] = { (const float*)d_in[2],  (const float*)d_in[4],  (const float*)d_in[6],
                        (const float*)d_in[8],  (const float*)d_in[10], (const float*)d_in[12] };
  const float* B[6] = { (const float*)d_in[3],  (const float*)d_in[5],  (const float*)d_in[7],
                        (const float*)d_in[9],  (const float*)d_in[11], (const float*)d_in[13] };

  const size_t MD = (size_t)NTOK * DIM;
  const size_t DD = (size_t)DIM * DIM;
  const size_t NN = (size_t)NTOK * NTOK;

  bf16* ws   = (bf16*)d_ws;
  bf16* x1b  = ws;
  bf16* x2b  = x1b + MD;
  bf16* wt1  = x2b + MD;
  bf16* wt2  = wt1 + 3 * DD;
  float* bstack = (float*)(wt2 + 3 * DD);
  bf16* q1   = wt2 + 3 * DD + 16384;
  bf16* k1   = q1 + MD;
  bf16* q2   = k1 + MD;
  bf16* k2   = q2 + MD;
  bf16* v1r  = k2 + MD;
  bf16* v2r  = v1r + MD;
  bf16* v1T  = v2r + MD;
  bf16* v2T  = v1T + MD;
  bf16* probsb = v2T + MD;

  const size_t topBytes = ((size_t)(10 * MD + 6 * DD + 16384) + 2 * NN) * 2;
  const bool top = (ws_size >= topBytes);

  float* out    = (float*)d_out;
  float* ctx2   = out;
  float* probs2 = ctx2 + MD;
  float* ctx1   = probs2 + NN;
  float* probs1 = ctx1 + MD;

  const float scale = 1.0f / 32.0f;

  {
    int n4 = (int)(MD / 4);
    cast2_f32_bf16<<<(2 * n4 + 255) / 256, 256, 0, stream>>>(x1, x2, x1b, n4);
  }
  transpose_cast6<<<6 * (DIM / 32) * (DIM / 32), 256, 0, stream>>>(
      W[0], W[1], W[2], W[3], W[4], W[5], wt1);
  pack_bias<<<24, 256, 0, stream>>>(B[0], B[1], B[2], B[3], B[4], B[5], bstack);

  // fused QKV projection: A = [x1b;x2b] (16384 x 1024), N = 3072. grid 768.
  gemm256<5, false, false><<<64 * 12, 512, 0, stream>>>(
      x1b, wt1, nullptr, wt2, 2 * NTOK, 3 * DIM, DIM, 12, 768,
      bstack, bstack + 3 * DIM, 0.f,
      nullptr, nullptr, nullptr, nullptr,
      q1, k1, v1r, q2, k2, v2r);

  // v transpose: [8192,1024] -> [1024,8192], both inputs
  transpose_bf16<<<2 * (NTOK / 64) * (DIM / 64), 256, 0, stream>>>(
      (const short*)v1r, (short*)v1T, (const short*)v2r, (short*)v2T, NTOK, DIM);

  const int perQK = (NTOK / 256) * (NTOK / 256);  // 1024
  const int perPV = (NTOK / 256) * (DIM / 256);   // 128

  if (top) {
    // fused dual QK: 2048 blocks, XCD-bijective swizzle.
    gemm256<4, true, false><<<2 * perQK, 512, 0, stream>>>(
        q1, k2, q2, k1, NTOK, NTOK, DIM, 32, perQK,
        nullptr, nullptr, scale,
        probs2, probs1, probsb, probsb + NN,
        nullptr, nullptr, nullptr, nullptr, nullptr, nullptr);
    // fused dual PV: 256 blocks, MMAJ mapping (XCD owns complete m-rows -> A-panel L2-resident).
    gemm256<3, true, true><<<2 * perPV, 512, 0, stream>>>(
        probsb, v2T, probsb + NN, v1T, NTOK, DIM, NTOK, 4, perPV,
        nullptr, nullptr, 0.f,
        ctx2, ctx1, nullptr, nullptr,
        nullptr, nullptr, nullptr, nullptr, nullptr, nullptr);
  } else {
    gemm256<2, false, false><<<perQK, 512, 0, stream>>>(
        q1, k2, nullptr, nullptr, NTOK, NTOK, DIM, 32, perQK,
        nullptr, nullptr, scale,
        probs2, nullptr, nullptr, nullptr,
        nullptr, nullptr, nullptr, nullptr, nullptr, nullptr);
    gemm_nt<3, true><<<(NTOK / 128) * (DIM / 128), 256, 0, stream>>>(
        probs2, v2T, NTOK, DIM, NTOK, 0.f, ctx2);
    gemm256<2, false, false><<<perQK, 512, 0, stream>>>(
        q2, k1, nullptr, nullptr, NTOK, NTOK, DIM, 32, perQK,
        nullptr, nullptr, scale,
        probs1, nullptr, nullptr, nullptr,
        nullptr, nullptr, nullptr, nullptr, nullptr, nullptr);
    gemm_nt<3, true><<<(NTOK / 128) * (DIM / 128), 256, 0, stream>>>(
        probs1, v1T, NTOK, DIM, NTOK, 0.f, ctx1);
  }
}